// Round 3
// baseline (9788.130 us; speedup 1.0000x reference)
//
#include <hip/hip_runtime.h>
#include <cmath>

#define B_ 16
#define T_ 2048
#define D_ 512
#define H_ 512

// ---------------------------------------------------------------------------
// Phase 1: XW[m, n] = x[m, :] @ W_xh[:, n] + bias[n] -> d_out.
// M = 32768, K = 512, N = 512. fp32, 128x128 tile, 8x8 acc per thread.
// ---------------------------------------------------------------------------
__global__ __launch_bounds__(256) void gemm_xw(
    const float* __restrict__ x,     // [M, K]
    const float* __restrict__ Wxh,   // [K, N]
    const float* __restrict__ bias,  // [N]
    float* __restrict__ out)         // [M, N]
{
    const int tid = threadIdx.x;
    const int n0 = blockIdx.x * 128;
    const int m0 = blockIdx.y * 128;

    __shared__ float As[8][132];  // [k][m], +4 pad
    __shared__ float Bs[8][132];  // [k][n]

    const int tx = tid & 15, ty = tid >> 4;
    float acc[8][8] = {};

    // A tile: 128 rows x 8 k. One float4 per thread (transposed store).
    const int arow = tid >> 1;
    const int akq  = (tid & 1) * 4;
    // B tile: 8 rows x 128 cols. One float4 per thread.
    const int brow = tid >> 5;
    const int bcol = (tid & 31) * 4;

    for (int k0 = 0; k0 < D_; k0 += 8) {
        float4 a4 = *(const float4*)(x + (size_t)(m0 + arow) * D_ + k0 + akq);
        float4 b4 = *(const float4*)(Wxh + (size_t)(k0 + brow) * H_ + n0 + bcol);
        __syncthreads();  // previous iter done reading LDS
        As[akq + 0][arow] = a4.x;
        As[akq + 1][arow] = a4.y;
        As[akq + 2][arow] = a4.z;
        As[akq + 3][arow] = a4.w;
        *(float4*)(&Bs[brow][bcol]) = b4;
        __syncthreads();
#pragma unroll
        for (int kk = 0; kk < 8; ++kk) {
            float4 a0 = *(const float4*)(&As[kk][ty * 8]);
            float4 a1 = *(const float4*)(&As[kk][ty * 8 + 4]);
            float4 b0 = *(const float4*)(&Bs[kk][tx * 8]);
            float4 b1 = *(const float4*)(&Bs[kk][tx * 8 + 4]);
            float a_[8] = {a0.x, a0.y, a0.z, a0.w, a1.x, a1.y, a1.z, a1.w};
            float b_[8] = {b0.x, b0.y, b0.z, b0.w, b1.x, b1.y, b1.z, b1.w};
#pragma unroll
            for (int i = 0; i < 8; ++i)
#pragma unroll
                for (int j = 0; j < 8; ++j) acc[i][j] += a_[i] * b_[j];
        }
    }

    const float4 bv0 = *(const float4*)(bias + n0 + tx * 8);
    const float4 bv1 = *(const float4*)(bias + n0 + tx * 8 + 4);
    const float bb[8] = {bv0.x, bv0.y, bv0.z, bv0.w, bv1.x, bv1.y, bv1.z, bv1.w};
#pragma unroll
    for (int i = 0; i < 8; ++i) {
        const int m = m0 + ty * 8 + i;
        float4 o0, o1;
        o0.x = acc[i][0] + bb[0]; o0.y = acc[i][1] + bb[1];
        o0.z = acc[i][2] + bb[2]; o0.w = acc[i][3] + bb[3];
        o1.x = acc[i][4] + bb[4]; o1.y = acc[i][5] + bb[5];
        o1.z = acc[i][6] + bb[6]; o1.w = acc[i][7] + bb[7];
        *(float4*)(out + (size_t)m * H_ + n0 + tx * 8)     = o0;
        *(float4*)(out + (size_t)m * H_ + n0 + tx * 8 + 4) = o1;
    }
}

// ---------------------------------------------------------------------------
// Phase 2: recurrence. 8 WGs x 512 thr per batch; WG (b,s) owns h cols
// [64s,64s+64), W slice register-resident. Exchange = packed u64
// (tag<<32 | float bits), double-buffered by tag&1.
//   FAST path: blockIdx = s*16+b puts all 8 WGs of batch b on XCD b%8
//   (round-robin heuristic), so producer store sc0 (write-through to the
//   shared per-XCD L2) + consumer load sc0 (L1-bypass, L2 hit) is coherent
//   at ~L2 latency.
//   SLOW path (correctness regardless of mapping): producer ALSO publishes
//   agent-scope (L3-coherent); consumers that time out on the fast buffer
//   stickily switch to polling the slow buffer. Never hangs, never stale:
//   readiness is the tag inside the same naturally-atomic 8B word.
// ---------------------------------------------------------------------------
#define FAST_SPIN 20000

__global__ __launch_bounds__(512) void rnn_rec(
    const float* __restrict__ Whh,           // [H_][H_] row-major
    float* __restrict__ out,                 // [B_][T_][H_], pre-filled XW+b
    unsigned long long* __restrict__ ws)     // fast[16][2][512], slow[...]
{
    const int tid = threadIdx.x;
    const int b = blockIdx.x & 15;
    const int s = blockIdx.x >> 4;
    const int j = tid & 63;   // column within slice
    const int p = tid >> 6;   // wave index == row block
    const int col = (s << 6) + j;

    __shared__ float h_lds[H_];
    __shared__ float part[8 * 64];

    float W_reg[64];
#pragma unroll
    for (int r = 0; r < 64; ++r)
        W_reg[r] = Whh[(size_t)(p * 64 + r) * H_ + col];

    h_lds[tid] = 0.0f;
    __syncthreads();

    float* outb = out + (size_t)b * T_ * H_;
    unsigned long long* fastb = ws + (size_t)b * 2 * H_;
    unsigned long long* slowb = ws + (size_t)B_ * 2 * H_ + (size_t)b * 2 * H_;

    float xw0 = 0.0f, xw1 = 0.0f;
    if (p == 0) {
        xw0 = outb[(size_t)0 * H_ + col];
        xw1 = outb[(size_t)1 * H_ + col];
    }

    bool use_fast = true;  // sticky, per thread

    for (int t = 0; t < T_; ++t) {
        // ---- partial dot: rows [64p, 64p+64) of column `col` ----
        // all lanes of wave p read the same addresses -> LDS broadcast
        float acc = 0.0f;
        const float4* hv = (const float4*)(h_lds + (p << 6));
#pragma unroll
        for (int i = 0; i < 16; ++i) {
            float4 h4 = hv[i];
            acc += h4.x * W_reg[4 * i + 0];
            acc += h4.y * W_reg[4 * i + 1];
            acc += h4.z * W_reg[4 * i + 2];
            acc += h4.w * W_reg[4 * i + 3];
        }
        part[tid] = acc;
        __syncthreads();  // (1) part ready; h_lds(t-1) fully consumed

        const unsigned int tag = (unsigned int)(t + 1);
        const int slot = (t + 1) & 1;
        const size_t base = (size_t)slot * H_;

        if (p == 0) {
            float ssum = xw0;
#pragma unroll
            for (int q = 0; q < 8; ++q) ssum += part[q * 64 + j];
            union { unsigned int u; float f; } cv;
            cv.f = tanhf(ssum);
            unsigned long long pv =
                ((unsigned long long)tag << 32) | (unsigned long long)cv.u;
            // fast publish: write-through to this XCD's L2
            unsigned long long* fdst = fastb + base + col;
            asm volatile("global_store_dwordx2 %0, %1, off sc0"
                         :: "v"(fdst), "v"(pv) : "memory");
            // slow publish: device-coherent (L3)
            __hip_atomic_store(slowb + base + col, pv, __ATOMIC_RELAXED,
                               __HIP_MEMORY_SCOPE_AGENT);
            outb[(size_t)t * H_ + col] = cv.f;
            h_lds[col] = cv.f;
            xw0 = xw1;
            xw1 = (t + 2 < T_) ? outb[(size_t)(t + 2) * H_ + col] : 0.0f;
        } else {
            const int q = (p == s) ? 0 : p;
            const size_t idx = base + (q << 6) + j;
            unsigned long long v = 0;
            if (use_fast) {
                unsigned long long* fsrc = fastb + idx;
                int spins = FAST_SPIN;
                for (;;) {
                    asm volatile(
                        "global_load_dwordx2 %0, %1, off sc0\n\t"
                        "s_waitcnt vmcnt(0)"
                        : "=v"(v) : "v"(fsrc) : "memory");
                    if ((unsigned int)(v >> 32) >= tag) break;
                    if (--spins == 0) { use_fast = false; break; }
                }
            }
            if (!use_fast) {
                unsigned long long* ssrc = slowb + idx;
                do {
                    v = __hip_atomic_load(ssrc, __ATOMIC_RELAXED,
                                          __HIP_MEMORY_SCOPE_AGENT);
                } while ((unsigned int)(v >> 32) < tag);
            }
            union { unsigned int u; float f; } cv;
            cv.u = (unsigned int)v;
            h_lds[(q << 6) + j] = cv.f;
        }
        __syncthreads();  // (2) h_lds now holds h_t
    }
}

extern "C" void kernel_launch(void* const* d_in, const int* in_sizes, int n_in,
                              void* d_out, int out_size, void* d_ws,
                              size_t ws_size, hipStream_t stream) {
    const float* x    = (const float*)d_in[0];  // [B,T,D]
    const float* Wxh  = (const float*)d_in[1];  // [D,H]
    const float* Whh  = (const float*)d_in[2];  // [H,H]
    const float* bias = (const float*)d_in[3];  // [H]
    // d_in[4] = A, unused in forward
    float* out = (float*)d_out;

    // comm buffers: fast[16][2][512] + slow[16][2][512] u64 = 256 KB.
    // Tags must start at 0 (harness poisons ws with 0xAA).
    hipMemsetAsync(d_ws, 0,
                   (size_t)2 * B_ * 2 * H_ * sizeof(unsigned long long),
                   stream);

    dim3 ggrid(H_ / 128, (B_ * T_) / 128, 1);
    gemm_xw<<<ggrid, 256, 0, stream>>>(x, Wxh, bias, out);

    rnn_rec<<<128, 512, 0, stream>>>(Whh, out, (unsigned long long*)d_ws);
}

// Round 4
// 3085.602 us; speedup vs baseline: 3.1722x; 3.1722x over previous
//
#include <hip/hip_runtime.h>
#include <cmath>

#define B_ 16
#define T_ 2048
#define D_ 512
#define H_ 512

// ---------------------------------------------------------------------------
// Phase 1: XW[m, n] = x[m, :] @ W_xh[:, n] + bias[n] -> d_out.
// M = 32768, K = 512, N = 512. fp32, 128x128 tile, 8x8 acc per thread.
// ---------------------------------------------------------------------------
__global__ __launch_bounds__(256) void gemm_xw(
    const float* __restrict__ x,     // [M, K]
    const float* __restrict__ Wxh,   // [K, N]
    const float* __restrict__ bias,  // [N]
    float* __restrict__ out)         // [M, N]
{
    const int tid = threadIdx.x;
    const int n0 = blockIdx.x * 128;
    const int m0 = blockIdx.y * 128;

    __shared__ float As[8][132];  // [k][m], +4 pad
    __shared__ float Bs[8][132];  // [k][n]

    const int tx = tid & 15, ty = tid >> 4;
    float acc[8][8] = {};

    const int arow = tid >> 1;
    const int akq  = (tid & 1) * 4;
    const int brow = tid >> 5;
    const int bcol = (tid & 31) * 4;

    for (int k0 = 0; k0 < D_; k0 += 8) {
        float4 a4 = *(const float4*)(x + (size_t)(m0 + arow) * D_ + k0 + akq);
        float4 b4 = *(const float4*)(Wxh + (size_t)(k0 + brow) * H_ + n0 + bcol);
        __syncthreads();
        As[akq + 0][arow] = a4.x;
        As[akq + 1][arow] = a4.y;
        As[akq + 2][arow] = a4.z;
        As[akq + 3][arow] = a4.w;
        *(float4*)(&Bs[brow][bcol]) = b4;
        __syncthreads();
#pragma unroll
        for (int kk = 0; kk < 8; ++kk) {
            float4 a0 = *(const float4*)(&As[kk][ty * 8]);
            float4 a1 = *(const float4*)(&As[kk][ty * 8 + 4]);
            float4 b0 = *(const float4*)(&Bs[kk][tx * 8]);
            float4 b1 = *(const float4*)(&Bs[kk][tx * 8 + 4]);
            float a_[8] = {a0.x, a0.y, a0.z, a0.w, a1.x, a1.y, a1.z, a1.w};
            float b_[8] = {b0.x, b0.y, b0.z, b0.w, b1.x, b1.y, b1.z, b1.w};
#pragma unroll
            for (int i = 0; i < 8; ++i)
#pragma unroll
                for (int j = 0; j < 8; ++j) acc[i][j] += a_[i] * b_[j];
        }
    }

    const float4 bv0 = *(const float4*)(bias + n0 + tx * 8);
    const float4 bv1 = *(const float4*)(bias + n0 + tx * 8 + 4);
    const float bb[8] = {bv0.x, bv0.y, bv0.z, bv0.w, bv1.x, bv1.y, bv1.z, bv1.w};
#pragma unroll
    for (int i = 0; i < 8; ++i) {
        const int m = m0 + ty * 8 + i;
        float4 o0, o1;
        o0.x = acc[i][0] + bb[0]; o0.y = acc[i][1] + bb[1];
        o0.z = acc[i][2] + bb[2]; o0.w = acc[i][3] + bb[3];
        o1.x = acc[i][4] + bb[4]; o1.y = acc[i][5] + bb[5];
        o1.z = acc[i][6] + bb[6]; o1.w = acc[i][7] + bb[7];
        *(float4*)(out + (size_t)m * H_ + n0 + tx * 8)     = o0;
        *(float4*)(out + (size_t)m * H_ + n0 + tx * 8 + 4) = o1;
    }
}

// ---------------------------------------------------------------------------
// Phase 2: recurrence (round-2 exchange + two latency fixes).
// 8 WGs x 512 thr per batch; WG (b,s) owns h cols [64s,64s+64). Exchange =
// packed u64 (tag<<32 | float bits), RELAXED agent-scope (cache-bypassing),
// double-buffered by tag&1; producer lead bounded to 1 step by the
// consume-before-produce chain, so 2 slots cannot be overrun.
//
// Fix 1: hand-rolled LDS-only barriers (s_waitcnt lgkmcnt(0); s_barrier).
//   __syncthreads() drains vmcnt(0) too, putting wave0's HBM prefetch loads
//   and store-acks on the critical path every step. All inter-wave data here
//   moves through LDS; global exchange is self-synchronized by the in-word
//   tag, so vmcnt drain at the barrier is semantically unneeded.
//   Slot-reuse safety (publish@t must not pass publish@t-2 in flight):
//   wave0 drains vmcnt(0) at the TOP of its step, where all in-flight ops
//   are >= 1 step old (~free).
// Fix 2: __launch_bounds__(512, 2). Round 2 compiled to 44 VGPRs -> W_reg
//   was NOT register-resident (re-fetched from L1/L2 in the dot loop each
//   step). 128 WGs on 256 CUs only need 1 WG/CU, so allow ~256 VGPRs.
// ---------------------------------------------------------------------------
__device__ __forceinline__ void bar_lds() {
    asm volatile("s_waitcnt lgkmcnt(0)\n\ts_barrier" ::: "memory");
}

__global__ __launch_bounds__(512, 2) void rnn_rec(
    const float* __restrict__ Whh,           // [H_][H_] row-major
    float* __restrict__ out,                 // [B_][T_][H_], pre-filled XW+b
    unsigned long long* __restrict__ ws)     // [B_][2][H_] packed (tag,val)
{
    const int tid = threadIdx.x;
    const int b = blockIdx.x & 15;
    const int s = blockIdx.x >> 4;
    const int j = tid & 63;   // column within slice
    const int p = tid >> 6;   // wave index == row block (rows 64p..64p+63)
    const int col = (s << 6) + j;

    __shared__ float h_lds[H_];
    __shared__ float part[8 * 64];

    // Register-resident W slice: W_reg[r] = Whh[64p + r][col]
    float W_reg[64];
#pragma unroll
    for (int r = 0; r < 64; ++r)
        W_reg[r] = Whh[(size_t)(p * 64 + r) * H_ + col];

    h_lds[tid] = 0.0f;  // h_0 = 0
    __syncthreads();

    float* outb = out + (size_t)b * T_ * H_;
    unsigned long long* wsb = ws + (size_t)b * 2 * H_;

    // xw prefetch pipeline (wave 0 consumes xw; 2-step lookahead gives the
    // loads a full step of slack before their vmcnt wait at use)
    float xw0 = 0.0f, xw1 = 0.0f;
    if (p == 0) {
        xw0 = outb[(size_t)0 * H_ + col];
        xw1 = outb[(size_t)1 * H_ + col];
    }

    for (int t = 0; t < T_; ++t) {
        // ---- partial dot: rows [64p, 64p+64) of column `col` ----
        // wave-uniform LDS addresses -> broadcast reads, conflict-free
        float acc = 0.0f;
        const float4* hv = (const float4*)(h_lds + (p << 6));
#pragma unroll
        for (int i = 0; i < 16; ++i) {
            float4 h4 = hv[i];
            acc += h4.x * W_reg[4 * i + 0];
            acc += h4.y * W_reg[4 * i + 1];
            acc += h4.z * W_reg[4 * i + 2];
            acc += h4.w * W_reg[4 * i + 3];
        }
        part[tid] = acc;
        bar_lds();  // (1) part ready; h_lds(t-1) fully consumed (LDS only)

        const unsigned int tag = (unsigned int)(t + 1);
        const int slot = (t + 1) & 1;
        unsigned long long* wslot = wsb + (size_t)slot * H_;

        if (p == 0) {
            // slot-reuse guard: everything in flight is >= 1 step old
            asm volatile("s_waitcnt vmcnt(0)" ::: "memory");
            float ssum = xw0;
#pragma unroll
            for (int q = 0; q < 8; ++q) ssum += part[q * 64 + j];
            union { unsigned int u; float f; } cv;
            cv.f = tanhf(ssum);
            unsigned long long pv =
                ((unsigned long long)tag << 32) | (unsigned long long)cv.u;
            // publish FIRST (remote pollers wait on this)
            __hip_atomic_store(wslot + col, pv, __ATOMIC_RELAXED,
                               __HIP_MEMORY_SCOPE_AGENT);
            outb[(size_t)t * H_ + col] = cv.f;  // final output (plain)
            h_lds[col] = cv.f;                  // local copy for next step
            xw0 = xw1;
            xw1 = (t + 2 < T_) ? outb[(size_t)(t + 2) * H_ + col] : 0.0f;
        } else {
            // gather one remote slice: wave p -> slice p; wave s (local
            // slice) covers slice 0 for producer-wave 0
            const int q = (p == s) ? 0 : p;
            unsigned long long* src = wslot + (q << 6) + j;
            unsigned long long v;
            do {
                v = __hip_atomic_load(src, __ATOMIC_RELAXED,
                                      __HIP_MEMORY_SCOPE_AGENT);
            } while ((unsigned int)(v >> 32) < tag);
            union { unsigned int u; float f; } cv;
            cv.u = (unsigned int)v;
            h_lds[(q << 6) + j] = cv.f;
        }
        bar_lds();  // (2) h_lds now holds h_t (LDS only)
    }
}

extern "C" void kernel_launch(void* const* d_in, const int* in_sizes, int n_in,
                              void* d_out, int out_size, void* d_ws,
                              size_t ws_size, hipStream_t stream) {
    const float* x    = (const float*)d_in[0];  // [B,T,D]
    const float* Wxh  = (const float*)d_in[1];  // [D,H]
    const float* Whh  = (const float*)d_in[2];  // [H,H]
    const float* bias = (const float*)d_in[3];  // [H]
    // d_in[4] = A, unused in forward
    float* out = (float*)d_out;

    // comm buffer: [16][2][512] x 8B = 128 KB; tags must start at 0
    // (harness poisons ws with 0xAA before every launch)
    hipMemsetAsync(d_ws, 0, (size_t)B_ * 2 * H_ * sizeof(unsigned long long),
                   stream);

    dim3 ggrid(H_ / 128, (B_ * T_) / 128, 1);
    gemm_xw<<<ggrid, 256, 0, stream>>>(x, Wxh, bias, out);

    rnn_rec<<<128, 512, 0, stream>>>(Whh, out, (unsigned long long*)d_ws);
}

// Round 5
// 2966.126 us; speedup vs baseline: 3.3000x; 1.0403x over previous
//
#include <hip/hip_runtime.h>
#include <cmath>

#define B_ 16
#define T_ 2048
#define D_ 512
#define H_ 512

// ---------------------------------------------------------------------------
// Phase 1: XW[m, n] = x[m, :] @ W_xh[:, n] + bias[n] -> d_out.
// M = 32768, K = 512, N = 512. fp32, 128x128 tile, 8x8 acc per thread.
// ---------------------------------------------------------------------------
__global__ __launch_bounds__(256) void gemm_xw(
    const float* __restrict__ x,     // [M, K]
    const float* __restrict__ Wxh,   // [K, N]
    const float* __restrict__ bias,  // [N]
    float* __restrict__ out)         // [M, N]
{
    const int tid = threadIdx.x;
    const int n0 = blockIdx.x * 128;
    const int m0 = blockIdx.y * 128;

    __shared__ float As[8][132];  // [k][m], +4 pad
    __shared__ float Bs[8][132];  // [k][n]

    const int tx = tid & 15, ty = tid >> 4;
    float acc[8][8] = {};

    const int arow = tid >> 1;
    const int akq  = (tid & 1) * 4;
    const int brow = tid >> 5;
    const int bcol = (tid & 31) * 4;

    for (int k0 = 0; k0 < D_; k0 += 8) {
        float4 a4 = *(const float4*)(x + (size_t)(m0 + arow) * D_ + k0 + akq);
        float4 b4 = *(const float4*)(Wxh + (size_t)(k0 + brow) * H_ + n0 + bcol);
        __syncthreads();
        As[akq + 0][arow] = a4.x;
        As[akq + 1][arow] = a4.y;
        As[akq + 2][arow] = a4.z;
        As[akq + 3][arow] = a4.w;
        *(float4*)(&Bs[brow][bcol]) = b4;
        __syncthreads();
#pragma unroll
        for (int kk = 0; kk < 8; ++kk) {
            float4 a0 = *(const float4*)(&As[kk][ty * 8]);
            float4 a1 = *(const float4*)(&As[kk][ty * 8 + 4]);
            float4 b0 = *(const float4*)(&Bs[kk][tx * 8]);
            float4 b1 = *(const float4*)(&Bs[kk][tx * 8 + 4]);
            float a_[8] = {a0.x, a0.y, a0.z, a0.w, a1.x, a1.y, a1.z, a1.w};
            float b_[8] = {b0.x, b0.y, b0.z, b0.w, b1.x, b1.y, b1.z, b1.w};
#pragma unroll
            for (int i = 0; i < 8; ++i)
#pragma unroll
                for (int j = 0; j < 8; ++j) acc[i][j] += a_[i] * b_[j];
        }
    }

    const float4 bv0 = *(const float4*)(bias + n0 + tx * 8);
    const float4 bv1 = *(const float4*)(bias + n0 + tx * 8 + 4);
    const float bb[8] = {bv0.x, bv0.y, bv0.z, bv0.w, bv1.x, bv1.y, bv1.z, bv1.w};
#pragma unroll
    for (int i = 0; i < 8; ++i) {
        const int m = m0 + ty * 8 + i;
        float4 o0, o1;
        o0.x = acc[i][0] + bb[0]; o0.y = acc[i][1] + bb[1];
        o0.z = acc[i][2] + bb[2]; o0.w = acc[i][3] + bb[3];
        o1.x = acc[i][4] + bb[4]; o1.y = acc[i][5] + bb[5];
        o1.z = acc[i][6] + bb[6]; o1.w = acc[i][7] + bb[7];
        *(float4*)(out + (size_t)m * H_ + n0 + tx * 8)     = o0;
        *(float4*)(out + (size_t)m * H_ + n0 + tx * 8 + 4) = o1;
    }
}

// ---------------------------------------------------------------------------
// Phase 2: recurrence.
// 8 WGs x 512 thr per batch; WG (b,s) owns h cols [64s,64s+64). Exchange =
// packed u64 (tag<<32 | float bits), RELAXED agent-scope (cache-bypassing),
// double-buffered by tag&1; producer lead bounded to 1 step.
//
// KEY FIX vs round 4: W_reg was never register-resident (VGPR_Count=44!).
// Whh is const+restrict, so the compiler rematerialized the loads inside
// the dot loop -> 128 KB/WG re-read from L2 EVERY step (~2300 cy, the real
// bottleneck; why rounds 2 and 4 tied). Loading W via asm-volatile
// global_load_dword makes the values asm-defined: they CANNOT be
// rematerialized and must stay in VGPRs (~110 used, budget 256 via
// __launch_bounds__(512,2) -> 1 WG/CU, 128 WGs on 256 CUs).
//
// Barriers are LDS-only (lgkmcnt) so wave0's HBM prefetch/store traffic is
// never drained on the barrier path; slot-reuse safety via a vmcnt(0) guard
// at the top of wave0's step (all in-flight ops there are >=1 step old).
// ---------------------------------------------------------------------------
__device__ __forceinline__ void bar_lds() {
    asm volatile("s_waitcnt lgkmcnt(0)\n\ts_barrier" ::: "memory");
}

__global__ __launch_bounds__(512, 2) void rnn_rec(
    const float* __restrict__ Whh,           // [H_][H_] row-major
    float* __restrict__ out,                 // [B_][T_][H_], pre-filled XW+b
    unsigned long long* __restrict__ ws)     // [B_][2][H_] packed (tag,val)
{
    const int tid = threadIdx.x;
    const int b = blockIdx.x & 15;
    const int s = blockIdx.x >> 4;
    const int j = tid & 63;   // column within slice
    const int p = tid >> 6;   // wave index == row block (rows 64p..64p+63)
    const int col = (s << 6) + j;

    __shared__ float h_lds[H_];
    __shared__ float part[8 * 64];

    // W slice, FORCED register-resident: W_reg[r] = Whh[64p + r][col].
    // asm-defined values cannot be rematerialized by the compiler.
    float W_reg[64];
    {
        const float* wbase = Whh + (size_t)(p * 64) * H_ + col;
#pragma unroll
        for (int r = 0; r < 64; ++r) {
            const float* addr = wbase + (size_t)r * H_;
            asm volatile("global_load_dword %0, %1, off"
                         : "=v"(W_reg[r]) : "v"(addr));
        }
        asm volatile("s_waitcnt vmcnt(0)" ::: "memory");
    }

    h_lds[tid] = 0.0f;  // h_0 = 0
    __syncthreads();

    float* outb = out + (size_t)b * T_ * H_;
    unsigned long long* wsb = ws + (size_t)b * 2 * H_;

    // xw prefetch pipeline, depth 3 (wave 0 consumes xw)
    float xw0 = 0.0f, xw1 = 0.0f, xw2 = 0.0f;
    if (p == 0) {
        xw0 = outb[(size_t)0 * H_ + col];
        xw1 = outb[(size_t)1 * H_ + col];
        xw2 = outb[(size_t)2 * H_ + col];
    }

    for (int t = 0; t < T_; ++t) {
        // ---- partial dot: rows [64p, 64p+64) of column `col` ----
        // wave-uniform LDS addresses -> broadcast reads, conflict-free
        float acc = 0.0f;
        const float4* hv = (const float4*)(h_lds + (p << 6));
#pragma unroll
        for (int i = 0; i < 16; ++i) {
            float4 h4 = hv[i];
            acc += h4.x * W_reg[4 * i + 0];
            acc += h4.y * W_reg[4 * i + 1];
            acc += h4.z * W_reg[4 * i + 2];
            acc += h4.w * W_reg[4 * i + 3];
        }
        part[tid] = acc;
        bar_lds();  // (1) part ready; h_lds(t-1) fully consumed (LDS only)

        const unsigned int tag = (unsigned int)(t + 1);
        const int slot = (t + 1) & 1;
        unsigned long long* wslot = wsb + (size_t)slot * H_;

        if (p == 0) {
            // slot-reuse guard: everything in flight is >= 1 step old
            asm volatile("s_waitcnt vmcnt(0)" ::: "memory");
            float ssum = xw0;
#pragma unroll
            for (int q = 0; q < 8; ++q) ssum += part[q * 64 + j];
            union { unsigned int u; float f; } cv;
            cv.f = tanhf(ssum);
            unsigned long long pv =
                ((unsigned long long)tag << 32) | (unsigned long long)cv.u;
            // publish FIRST (remote pollers wait on this)
            __hip_atomic_store(wslot + col, pv, __ATOMIC_RELAXED,
                               __HIP_MEMORY_SCOPE_AGENT);
            outb[(size_t)t * H_ + col] = cv.f;  // final output (plain)
            h_lds[col] = cv.f;                  // local copy for next step
            xw0 = xw1;
            xw1 = xw2;
            xw2 = (t + 3 < T_) ? outb[(size_t)(t + 3) * H_ + col] : 0.0f;
        } else {
            // gather one remote slice: wave p -> slice p; wave s (local
            // slice) covers slice 0 for producer-wave 0
            const int q = (p == s) ? 0 : p;
            unsigned long long* src = wslot + (q << 6) + j;
            unsigned long long v;
            do {
                v = __hip_atomic_load(src, __ATOMIC_RELAXED,
                                      __HIP_MEMORY_SCOPE_AGENT);
            } while ((unsigned int)(v >> 32) < tag);
            union { unsigned int u; float f; } cv;
            cv.u = (unsigned int)v;
            h_lds[(q << 6) + j] = cv.f;
        }
        bar_lds();  // (2) h_lds now holds h_t (LDS only)
    }
}

extern "C" void kernel_launch(void* const* d_in, const int* in_sizes, int n_in,
                              void* d_out, int out_size, void* d_ws,
                              size_t ws_size, hipStream_t stream) {
    const float* x    = (const float*)d_in[0];  // [B,T,D]
    const float* Wxh  = (const float*)d_in[1];  // [D,H]
    const float* Whh  = (const float*)d_in[2];  // [H,H]
    const float* bias = (const float*)d_in[3];  // [H]
    // d_in[4] = A, unused in forward
    float* out = (float*)d_out;

    // comm buffer: [16][2][512] x 8B = 128 KB; tags must start at 0
    // (harness poisons ws with 0xAA before every launch)
    hipMemsetAsync(d_ws, 0, (size_t)B_ * 2 * H_ * sizeof(unsigned long long),
                   stream);

    dim3 ggrid(H_ / 128, (B_ * T_) / 128, 1);
    gemm_xw<<<ggrid, 256, 0, stream>>>(x, Wxh, bias, out);

    rnn_rec<<<128, 512, 0, stream>>>(Whh, out, (unsigned long long*)d_ws);
}